// Round 13
// baseline (4926.744 us; speedup 1.0000x reference)
//
#include <hip/hip_runtime.h>
#include <cstdint>
#include <cstddef>
#include <cstdio>

using u16 = unsigned short;
using u32 = unsigned int;

typedef __attribute__((ext_vector_type(8))) __bf16 bf16x8;
typedef __attribute__((ext_vector_type(4))) float f32x4;

struct alignas(16) U128 { u32 w[4]; };
struct alignas(16) F4   { float x[4]; };
struct alignas(8)  US4  { u16 h[4]; };

#define DEVFN static __device__ __forceinline__

DEVFN u16 f2bf(float x) {
  union { float f; u32 u; } v; v.f = x;
  u32 r = v.u + 0x7fffu + ((v.u >> 16) & 1u);
  return (u16)(r >> 16);
}

DEVFN bf16x8 ld16(const u16* p) { return __builtin_bit_cast(bf16x8, *(const U128*)p); }

DEVFN f32x4 mfma16(bf16x8 a, bf16x8 b, f32x4 c) {
  return __builtin_amdgcn_mfma_f32_16x16x32_bf16(a, b, c, 0, 0, 0);
}

DEVFN void gload_lds16(const u16* g, u16* l) {
  __builtin_amdgcn_global_load_lds(
      (const __attribute__((address_space(1))) void*)g,
      (__attribute__((address_space(3))) void*)l, 16, 0, 0);
}

// fast gelu (exact erf via A&S 7.1.26, |err| <= 1.5e-7)
DEVFN float gelu(float x) {
  float z = fabsf(x) * 0.70710678118f;
  float t = __builtin_amdgcn_rcpf(1.f + 0.3275911f * z);
  float p = t * (0.254829592f + t * (-0.284496736f + t * (1.421413741f +
            t * (-1.453152027f + t * 1.061405429f))));
  float e = __expf(-z * z);
  float erfz = 1.f - p * e;
  erfz = copysignf(erfz, x);
  return 0.5f * x * (1.f + erfz);
}

// A-panel-locality dispatch remap (stride-8 preserves XCD; halved FETCH, R5).
DEVFN void remap_bid(int bid, int Mb, int Nb, int& bm, int& bn) {
  const int ngrp  = Mb >> 3;
  const int per   = Nb << 3;
  const int nfull = ngrp * per;
  if (bid < nfull) {
    const int bmg = bid / per;
    const int rem = bid - bmg * per;
    bn = rem >> 3;
    bm = (bmg << 3) + (rem & 7);
  } else {
    const int r = bid - nfull;
    const int q = r / Nb;
    bm = (ngrp << 3) + q;
    bn = r - q * Nb;
  }
}

// ---------------- dimensions ----------------
constexpr int SEQL   = 197;
constexpr int NB     = 64;
constexpr int NH     = 12;
constexpr int MROWS  = NB * SEQL;    // 12608 real rows
constexpr int MPAD   = 12672;        // 99 * 128
constexpr int MPAD2  = 12800;        // buffer sizing
constexpr int MPATCH = NB * 196;     // 12544
constexpr int SP     = 208;          // padded seq for Q/K (13*16)
constexpr int SP2    = 224;          // padded seq for Vt / P (7*32)
constexpr int BHN    = NB * NH;      // 768 (b,h) pairs

constexpr int QSZ    = 2304 * 128;   // per-block Wqkv elems
constexpr int WSZ    = 3072 * 768;   // per-block W1/W2 elems

// ---------------- workspace layout (bytes) ----------------
constexpr size_t OFF_X    = 0;                                          // fp32 residual [MPAD][768]
constexpr size_t OFF_ALN  = OFF_X    + (size_t)MPAD * 768 * 4;          // bf16 LN out  [MPAD2][768]
constexpr size_t OFF_H    = OFF_ALN  + (size_t)MPAD2 * 768 * 2;         // bf16 mlp mid [MPAD2][3072]
constexpr size_t OFF_WMAP = OFF_H    + (size_t)MPAD2 * 3072 * 2;        // bf16 [768][768]
constexpr size_t OFF_Q    = OFF_WMAP + (size_t)768 * 768 * 2;           // bf16 [BHN][SP][64]
constexpr size_t OFF_K    = OFF_Q    + (size_t)BHN * SP * 64 * 2;
constexpr size_t OFF_VT   = OFF_K    + (size_t)BHN * SP * 64 * 2;       // bf16 [BHN][64][SP2]
constexpr size_t OFF_PAT  = OFF_VT   + (size_t)BHN * 64 * SP2 * 2;      // bf16 [12544][768]
constexpr size_t OFF_POS  = OFF_PAT  + (size_t)MPATCH * 768 * 2;        // fp32 [197][768]
constexpr size_t OFF_WTS  = OFF_POS  + (size_t)SEQL * 768 * 4;          // bf16 weights
constexpr size_t WS_SMALL = OFF_WTS + (size_t)(QSZ + 2 * WSZ) * 2;      // 1-block slots
constexpr size_t WS_BIG   = OFF_WTS + (size_t)12 * (QSZ + 2 * WSZ) * 2; // all 12 hoisted

// ---------------- small utility kernels ----------------
__global__ void zero_kernel(u32* __restrict__ p, long n) {
  long i = (long)blockIdx.x * 256 + threadIdx.x;
  long stride = (long)gridDim.x * 256;
  for (; i < n; i += stride) p[i] = 0u;
}

// zero only the pad regions of Q/K (rows 197..207) and Vt (cols 197..223)
__global__ void padzero_kernel(u16* __restrict__ Q, u16* __restrict__ Kp,
                               u16* __restrict__ Vt) {
  const int NQ32 = BHN * 352;          // 11 rows * 64 e / 2 per bh
  const int NV   = BHN * 64 * 27;
  int i = blockIdx.x * 256 + threadIdx.x;
  if (i < NQ32) {
    int bh = i / 352, r = i - bh * 352;
    ((u32*)(Q + ((size_t)bh * SP + 197) * 64))[r] = 0u;
  } else if (i < 2 * NQ32) {
    int j = i - NQ32;
    int bh = j / 352, r = j - bh * 352;
    ((u32*)(Kp + ((size_t)bh * SP + 197) * 64))[r] = 0u;
  } else if (i < 2 * NQ32 + NV) {
    int j = i - 2 * NQ32;
    int be = j / 27, s = j - be * 27;
    Vt[(size_t)be * SP2 + 197 + s] = 0;
  }
}

__global__ void cvt_kernel(const float* __restrict__ src, u16* __restrict__ dst, int n) {
  int i = blockIdx.x * 256 + threadIdx.x;
  if (i < n) dst[i] = f2bf(src[i]);
}

__global__ void pos_kernel(float* __restrict__ pos) {
  int i = blockIdx.x * 256 + threadIdx.x;
  if (i >= SEQL * 768) return;
  int s = i / 768, j = i - s * 768;
  float expo = (float)(j & ~1) * (1.0f / 768.0f);
  float ang  = (float)s * expf(-expo * logf(10000.0f));
  pos[i] = (j & 1) ? cosf(ang) : sinf(ang);
}

__global__ void cls_kernel(const float* __restrict__ cls, const float* __restrict__ pos,
                           float* __restrict__ X) {
  int b = blockIdx.x;
  for (int c = threadIdx.x; c < 768; c += 256)
    X[(size_t)b * SEQL * 768 + c] = cls[c] + pos[c];
}

__global__ void patchify_kernel(const float* __restrict__ img, u16* __restrict__ out) {
  int i = blockIdx.x * 256 + threadIdx.x;
  if (i >= MPATCH * 768) return;
  int m = i / 768, k = i - m * 768;
  int b = m / 196, p = m - b * 196;
  int py = p / 14, px = p - py * 14;
  int c = k >> 8, rem = k & 255, iy = rem >> 4, ix = rem & 15;
  float v = img[(((size_t)b * 3 + c) * 224 + py * 16 + iy) * 224 + px * 16 + ix];
  out[i] = f2bf(v);
}

// hoisted prep: ALL 12 blocks' Wqkv + W1 + W2 -> bf16 in one launch
__global__ void prep_all(const float* __restrict__ qw, const float* __restrict__ kw,
                         const float* __restrict__ vw, const float* __restrict__ w1,
                         const float* __restrict__ w2,
                         u16* __restrict__ Wq, u16* __restrict__ W1b,
                         u16* __restrict__ W2b) {
  const int NQ = 12 * QSZ;
  const int NV = 12 * (WSZ / 4);
  int i = blockIdx.x * 256 + threadIdx.x;
  if (i < NQ) {
    int blk = i / QSZ;
    int r = i - blk * QSZ;
    int n = r >> 7, kk = r & 127;
    int p = n / 768, ef = n - p * 768;
    int h = ef >> 6, e = ef & 63;
    float v = 0.f;
    if ((kk >> 6) == (h & 1)) {
      int d = kk & 63;
      const float* w = (p == 0) ? qw : (p == 1) ? kw : vw;
      v = w[(((size_t)blk * NH + h) * 64 + e) * 64 + d];
    }
    Wq[i] = f2bf(v);
  } else if (i < NQ + NV) {
    int j = (i - NQ) * 4;
    F4 v = *(const F4*)(w1 + j);
    US4 o;
    #pragma unroll
    for (int r = 0; r < 4; ++r) o.h[r] = f2bf(v.x[r]);
    *(US4*)(W1b + j) = o;
  } else if (i < NQ + 2 * NV) {
    int j = (i - NQ - NV) * 4;
    F4 v = *(const F4*)(w2 + j);
    US4 o;
    #pragma unroll
    for (int r = 0; r < 4; ++r) o.h[r] = f2bf(v.x[r]);
    *(US4*)(W2b + j) = o;
  }
}

// fallback per-block prep (small-ws path)
__global__ void prep_kernel(const float* __restrict__ qw, const float* __restrict__ kw,
                            const float* __restrict__ vw, const float* __restrict__ w1,
                            const float* __restrict__ w2,
                            u16* __restrict__ Wqkv, u16* __restrict__ W1b,
                            u16* __restrict__ W2b, int blk) {
  const int NV = WSZ / 4;
  int i = blockIdx.x * 256 + threadIdx.x;
  if (i < QSZ) {
    int n = i >> 7, kk = i & 127;
    int p = n / 768, ef = n - p * 768;
    int h = ef >> 6, e = ef & 63;
    float v = 0.f;
    if ((kk >> 6) == (h & 1)) {
      int d = kk & 63;
      const float* w = (p == 0) ? qw : (p == 1) ? kw : vw;
      v = w[(((size_t)blk * NH + h) * 64 + e) * 64 + d];
    }
    Wqkv[i] = f2bf(v);
  } else if (i < QSZ + NV) {
    int j = (i - QSZ) * 4;
    F4 v = *(const F4*)(w1 + (size_t)blk * WSZ + j);
    US4 o;
    #pragma unroll
    for (int r = 0; r < 4; ++r) o.h[r] = f2bf(v.x[r]);
    *(US4*)(W1b + j) = o;
  } else if (i < QSZ + 2 * NV) {
    int j = (i - QSZ - NV) * 4;
    F4 v = *(const F4*)(w2 + (size_t)blk * WSZ + j);
    US4 o;
    #pragma unroll
    for (int r = 0; r < 4; ++r) o.h[r] = f2bf(v.x[r]);
    *(US4*)(W2b + j) = o;
  }
}

// ---------------- layernorm: fp32 row -> bf16 row ----------------
__global__ __launch_bounds__(256) void ln_kernel(const float* __restrict__ X,
    const float* __restrict__ g, const float* __restrict__ b, u16* __restrict__ out) {
  int row  = blockIdx.x * 4 + (threadIdx.x >> 6);
  int lane = threadIdx.x & 63;
  const float* x = X + (size_t)row * 768 + lane * 12;
  F4 a0 = *(const F4*)(x);
  F4 a1 = *(const F4*)(x + 4);
  F4 a2 = *(const F4*)(x + 8);
  float v[12];
  #pragma unroll
  for (int j = 0; j < 4; ++j) { v[j] = a0.x[j]; v[4 + j] = a1.x[j]; v[8 + j] = a2.x[j]; }
  float s = 0.f, q = 0.f;
  #pragma unroll
  for (int j = 0; j < 12; ++j) { s += v[j]; q += v[j] * v[j]; }
  #pragma unroll
  for (int d = 1; d < 64; d <<= 1) { s += __shfl_xor(s, d); q += __shfl_xor(q, d); }
  float mu  = s * (1.f / 768.f);
  float var = q * (1.f / 768.f) - mu * mu;
  float rs  = rsqrtf(var + 1e-5f);
  const float* gp = g + lane * 12;
  const float* bp = b + lane * 12;
  u16* op = out + (size_t)row * 768 + lane * 12;
  u16 o[12];
  #pragma unroll
  for (int j = 0; j < 12; ++j) o[j] = f2bf((v[j] - mu) * rs * gp[j] + bp[j]);
  #pragma unroll
  for (int c = 0; c < 3; ++c) {
    US4 w; w.h[0] = o[c*4]; w.h[1] = o[c*4+1]; w.h[2] = o[c*4+2]; w.h[3] = o[c*4+3];
    *(US4*)(op + c * 4) = w;
  }
}

enum { EPI_PATCH = 0, EPI_QKV = 1, EPI_GELU = 2, EPI_RESID = 3 };

// ========== unified 128x128 BK=32 4-wave GEMM, TRIPLE-buffered, counted vmcnt ======
// (r8/r10 proven structure — used for PATCH and RESID.)
template<int EPI>
__global__ __launch_bounds__(256, 3) void gemm128(
    const u16* __restrict__ A, const u16* __restrict__ B, int K, int lda, int ldb,
    int Mb, int Nb,
    const float* __restrict__ e0, const float* __restrict__ e1, const float* __restrict__ e2,
    float* __restrict__ f0, const float* __restrict__ f1,
    u16* __restrict__ o0, u16* __restrict__ o1, u16* __restrict__ o2) {
  __shared__ u16 Ab[3][128 * 32];
  __shared__ u16 Bb[3][128 * 32];
  const int tid  = threadIdx.x;
  const int wave = tid >> 6, lane = tid & 63;
  int bm, bn;
  remap_bid(blockIdx.x, Mb, Nb, bm, bn);
  const int fr = lane & 15, fg = lane >> 4;
  const int srow = wave * 16 + (lane >> 2);
  const int gcol = ((lane & 3) ^ ((lane >> 3) & 3)) * 8;
  const u16* gA = A + (size_t)(bm * 128 + srow) * lda + gcol;
  const u16* gB = B + (size_t)(bn * 128 + srow) * ldb + gcol;
  const int wm = (wave >> 1) * 64, wn = (wave & 1) * 64;
  const int sl = (fg ^ ((fr >> 1) & 3)) * 8;
  const int nt = K >> 5;

  auto STAGE = [&](int c, int t) {
    gload_lds16(gA + t * 32,                    &Ab[c][0] + wave * 512);
    gload_lds16(gA + t * 32 + (size_t)64 * lda, &Ab[c][0] + wave * 512 + 2048);
    gload_lds16(gB + t * 32,                    &Bb[c][0] + wave * 512);
    gload_lds16(gB + t * 32 + (size_t)64 * ldb, &Bb[c][0] + wave * 512 + 2048);
  };

  f32x4 acc[4][4] = {};
  STAGE(0, 0);
  if (nt > 1) STAGE(1, 1);
  int bi = 0;
  for (int t = 0; t < nt; ++t) {
    if (t + 1 < nt) asm volatile("s_waitcnt vmcnt(4)" ::: "memory");
    else            asm volatile("s_waitcnt vmcnt(0)" ::: "memory");
    __builtin_amdgcn_s_barrier();
    if (t + 2 < nt) { int si = bi + 2; if (si >= 3) si -= 3; STAGE(si, t + 2); }
    const u16* ab   = &Ab[bi][0];
    const u16* bbuf = &Bb[bi][0];
    bf16x8 af[4], bfv[4];
    #pragma unroll
    for (int i = 0; i < 4; ++i) af[i]  = ld16(ab + (wm + i * 16 + fr) * 32 + sl);
    #pragma unroll
    for (int j = 0; j < 4; ++j) bfv[j] = ld16(bbuf + (wn + j * 16 + fr) * 32 + sl);
    __builtin_amdgcn_s_setprio(1);
    #pragma unroll
    for (int i = 0; i < 4; ++i)
      #pragma unroll
      for (int j = 0; j < 4; ++j)
        acc[i][j] = mfma16(af[i], bfv[j], acc[i][j]);
    __builtin_amdgcn_s_setprio(0);
    bi = (bi + 1 == 3) ? 0 : bi + 1;
  }

  // epilogue: C frag col = fr, row = fg*4 + r
  #pragma unroll
  for (int i = 0; i < 4; ++i) {
    #pragma unroll
    for (int r = 0; r < 4; ++r) {
      const int m = bm * 128 + wm + i * 16 + fg * 4 + r;
      if constexpr (EPI == EPI_PATCH) {
        const int bb = m / 196;
        const int s  = m - bb * 196 + 1;
        float* xrow = f0 + ((size_t)bb * SEQL + s) * 768;
        const float* prow = f1 + (size_t)s * 768;
        #pragma unroll
        for (int j = 0; j < 4; ++j) {
          const int n = bn * 128 + wn + j * 16 + fr;
          xrow[n] = acc[i][j][r] + e0[n] + prow[n];
        }
      } else { // EPI_RESID
        if (m < MROWS) {
          float* xrow = f0 + (size_t)m * 768;
          #pragma unroll
          for (int j = 0; j < 4; ++j) {
            const int n = bn * 128 + wn + j * 16 + fr;
            xrow[n] += acc[i][j][r] + e0[n];
          }
        }
      }
    }
  }
}

// ========== persistent/flattened GELU GEMM (M=12672, N=3072, K=768) ==============
__global__ __launch_bounds__(256, 3) void gemm128f_gelu(
    const u16* __restrict__ A, const u16* __restrict__ B,
    const float* __restrict__ e0, u16* __restrict__ o0,
    int ntiles, int nblocks) {
  __shared__ u16 Ab[3][128 * 32];
  __shared__ u16 Bb[3][128 * 32];
  constexpr int lda = 768, ldb = 768, nt = 24;   // K = 768
  const int tid = threadIdx.x, wave = tid >> 6, lane = tid & 63;
  const int fr = lane & 15, fg = lane >> 4;
  const int srow = wave * 16 + (lane >> 2);
  const int gcol = ((lane & 3) ^ ((lane >> 3) & 3)) * 8;
  const int wm = (wave >> 1) * 64, wn = (wave & 1) * 64;
  const int sl = (fg ^ ((fr >> 1) & 3)) * 8;
  const int myTiles = (ntiles - (int)blockIdx.x + nblocks - 1) / nblocks;
  const int total = myTiles * nt;

  int s_t  = blockIdx.x;
  int s_kk = 0;
  const u16 *s_gA, *s_gB;
  {
    int bm, bn; remap_bid(s_t, 99, 24, bm, bn);
    s_gA = A + (size_t)(bm * 128 + srow) * lda + gcol;
    s_gB = B + (size_t)(bn * 128 + srow) * ldb + gcol;
  }
  auto STAGE1 = [&](int c) {
    gload_lds16(s_gA + s_kk * 32,                    &Ab[c][0] + wave * 512);
    gload_lds16(s_gA + s_kk * 32 + (size_t)64 * lda, &Ab[c][0] + wave * 512 + 2048);
    gload_lds16(s_gB + s_kk * 32,                    &Bb[c][0] + wave * 512);
    gload_lds16(s_gB + s_kk * 32 + (size_t)64 * ldb, &Bb[c][0] + wave * 512 + 2048);
    if (++s_kk == nt) {
      s_kk = 0;
      s_t += nblocks;
      if (s_t < ntiles) {
        int bm, bn; remap_bid(s_t, 99, 24, bm, bn);
        s_gA = A + (size_t)(bm * 128 + srow) * lda + gcol;
        s_gB = B + (size_t)(bn * 128 + srow) * ldb + gcol;
      }
    }
  };

  STAGE1(0);
  if (total > 1) STAGE1(1);
  int bi = 0, g = 0;
  for (int t = blockIdx.x; t < ntiles; t += nblocks) {
    int bm, bn; remap_bid(t, 99, 24, bm, bn);
    f32x4 acc[4][4] = {};
    for (int k = 0; k < nt; ++k, ++g) {
      if (g + 1 < total) asm volatile("s_waitcnt vmcnt(4)" ::: "memory");
      else               asm volatile("s_waitcnt vmcnt(0)" ::: "memory");
      __builtin_amdgcn_s_barrier();
      if (g + 2 < total) { int si = bi + 2; if (si >= 3) si -= 3; STAGE1(si); }
      const u16* ab   = &Ab[bi][0];
      const u16* bbuf = &Bb[bi][0];
      bf16x8 af[4], bfv[4];
      #pragma unroll
      for (int i = 0; i < 4; ++i) af[i]  = ld16(ab + (wm + i * 16 + fr) * 32 + sl);
      #pragma unroll
      for (int j = 0; j < 4; ++j) bfv[j] = ld16(bbuf + (wn + j * 16 + fr) * 32 + sl);
      __builtin_amdgcn_s_setprio(1);
      #pragma unroll
      for (int i = 0; i < 4; ++i)
        #pragma unroll
        for (int j = 0; j < 4; ++j)
          acc[i][j] = mfma16(af[i], bfv[j], acc[i][j]);
      __builtin_amdgcn_s_setprio(0);
      bi = (bi + 1 == 3) ? 0 : bi + 1;
    }
    // epilogue (GELU)
    #pragma unroll
    for (int i = 0; i < 4; ++i) {
      #pragma unroll
      for (int r = 0; r < 4; ++r) {
        const int m = bm * 128 + wm + i * 16 + fg * 4 + r;
        u16* hrow = o0 + (size_t)m * 3072;
        #pragma unroll
        for (int j = 0; j < 4; ++j) {
          const int n = bn * 128 + wn + j * 16 + fr;
          hrow[n] = f2bf(gelu(acc[i][j][r] + e0[n]));
        }
      }
    }
  }
}

// ========== persistent/flattened QKV GEMM (M=12672, N=2304 compact-K=128) ==========
__global__ __launch_bounds__(256, 3) void qkv_flat(
    const u16* __restrict__ A, const u16* __restrict__ B,
    const float* __restrict__ e0, const float* __restrict__ e1, const float* __restrict__ e2,
    u16* __restrict__ o0, u16* __restrict__ o1, u16* __restrict__ o2,
    int ntiles, int nblocks) {
  __shared__ u16 Ab[3][128 * 32];
  __shared__ u16 Bb[3][128 * 32];
  constexpr int lda = 768, ldb = 128, nt = 4;   // compact K = 128
  const int tid = threadIdx.x, wave = tid >> 6, lane = tid & 63;
  const int fr = lane & 15, fg = lane >> 4;
  const int srow = wave * 16 + (lane >> 2);
  const int gcol = ((lane & 3) ^ ((lane >> 3) & 3)) * 8;
  const int wm = (wave >> 1) * 64, wn = (wave & 1) * 64;
  const int sl = (fg ^ ((fr >> 1) & 3)) * 8;
  const int myTiles = (ntiles - (int)blockIdx.x + nblocks - 1) / nblocks;
  if (myTiles <= 0) return;
  const int total = myTiles * nt;

  int s_t  = blockIdx.x;
  int s_kk = 0;
  const u16 *s_gA, *s_gB;
  {
    int bm, bn; remap_bid(s_t, 99, 18, bm, bn);
    s_gA = A + (bn % 6) * 128 + (size_t)(bm * 128 + srow) * lda + gcol;
    s_gB = B + (size_t)(bn * 128 + srow) * ldb + gcol;
  }
  auto STAGE1 = [&](int c) {
    gload_lds16(s_gA + s_kk * 32,                    &Ab[c][0] + wave * 512);
    gload_lds16(s_gA + s_kk * 32 + (size_t)64 * lda, &Ab[c][0] + wave * 512 + 2048);
    gload_lds16(s_gB + s_kk * 32,                    &Bb[c][0] + wave * 512);
    gload_lds16(s_gB + s_kk * 32 + (size_t)64 * ldb, &Bb[c][0] + wave * 512 + 2048);
    if (++s_kk == nt) {
      s_kk = 0;
      s_t += nblocks;
      if (s_t < ntiles) {
        int bm, bn; remap_bid(s_t, 99, 18, bm, bn);
        s_gA = A + (bn % 6) * 128 + (size_t)(bm * 128 + srow) * lda + gcol;
        s_gB = B + (size_t)(bn * 128 + srow) * ldb + gcol;
      }
    }
  };

  STAGE1(0);
  if (total > 1) STAGE1(1);
  int bi = 0, g = 0;
  for (int t = blockIdx.x; t < ntiles; t += nblocks) {
    int bm, bn; remap_bid(t, 99, 18, bm, bn);
    f32x4 acc[4][4] = {};
    #pragma unroll
    for (int k = 0; k < nt; ++k, ++g) {
      if (g + 1 < total) asm volatile("s_waitcnt vmcnt(4)" ::: "memory");
      else               asm volatile("s_waitcnt vmcnt(0)" ::: "memory");
      __builtin_amdgcn_s_barrier();
      if (g + 2 < total) { int si = bi + 2; if (si >= 3) si -= 3; STAGE1(si); }
      const u16* ab   = &Ab[bi][0];
      const u16* bbuf = &Bb[bi][0];
      bf16x8 af[4], bfv[4];
      #pragma unroll
      for (int i = 0; i < 4; ++i) af[i]  = ld16(ab + (wm + i * 16 + fr) * 32 + sl);
      #pragma unroll
      for (int j = 0; j < 4; ++j) bfv[j] = ld16(bbuf + (wn + j * 16 + fr) * 32 + sl);
      __builtin_amdgcn_s_setprio(1);
      #pragma unroll
      for (int i = 0; i < 4; ++i)
        #pragma unroll
        for (int j = 0; j < 4; ++j)
          acc[i][j] = mfma16(af[i], bfv[j], acc[i][j]);
      __builtin_amdgcn_s_setprio(0);
      bi = (bi + 1 == 3) ? 0 : bi + 1;
    }
    // epilogue (QKV scatter)
    #pragma unroll
    for (int i = 0; i < 4; ++i) {
      #pragma unroll
      for (int r = 0; r < 4; ++r) {
        const int m = bm * 128 + wm + i * 16 + fg * 4 + r;
        if (m < MROWS) {
          const int bb = m / 197;
          const int s  = m - bb * 197;
          #pragma unroll
          for (int j = 0; j < 4; ++j) {
            const int n = bn * 128 + wn + j * 16 + fr;
            const int p = n / 768;
            const int ef = n - p * 768;
            const int h = ef >> 6, e = ef & 63;
            const size_t bh = (size_t)bb * NH + h;
            if (p == 0)      o0[(bh * SP + s) * 64 + e] = f2bf((acc[i][j][r] + e0[ef]) * 0.125f);
            else if (p == 1) o1[(bh * SP + s) * 64 + e] = f2bf(acc[i][j][r] + e1[ef]);
            else             o2[(bh * 64 + e) * SP2 + s] = f2bf(acc[i][j][r] + e2[ef]);
          }
        }
      }
    }
  }
}

// ---------------- fused attention: one block per (b,h) ----------------
// K read direct from global/L2 (26 KB/head is L2-resident; staging it was
// Common-mistake #7 overhead) — LDS holds only P -> 3 blocks/CU.
__global__ __launch_bounds__(256, 3) void attn_kernel(const u16* __restrict__ Q,
    const u16* __restrict__ Km, const u16* __restrict__ Vt, float* __restrict__ X) {
  __shared__ u16  P[4][16 * SP2];      // 28 KB
  __shared__ float sums[4][16];
  const int bh = blockIdx.x;
  const int b = bh / NH, h = bh - b * NH;
  const int wave = threadIdx.x >> 6, lane = threadIdx.x & 63;
  const int fr = lane & 15, fg = lane >> 4;
  const u16* Qb = Q  + (size_t)bh * SP * 64;
  const u16* Kb = Km + (size_t)bh * SP * 64;
  const u16* Vb = Vt + (size_t)bh * 64 * SP2;
  u16* Pl = &P[wave][0];
  for (int qt = wave; qt < 13; qt += 4) {
    const int s0 = qt * 16;
    bf16x8 qf0 = ld16(Qb + (size_t)(s0 + fr) * 64 + fg * 8);
    bf16x8 qf1 = ld16(Qb + (size_t)(s0 + fr) * 64 + 32 + fg * 8);
    f32x4 sc[13];
    #pragma unroll
    for (int tf = 0; tf < 13; ++tf) {
      f32x4 a = {0.f, 0.f, 0.f, 0.f};
      bf16x8 k0 = ld16(Kb + (size_t)(tf * 16 + fr) * 64 + fg * 8);
      bf16x8 k1 = ld16(Kb + (size_t)(tf * 16 + fr) * 64 + 32 + fg * 8);
      a = mfma16(qf0, k0, a);
      a = mfma16(qf1, k1, a);
      sc[tf] = a;
    }
    float mx[4] = {-3e38f, -3e38f, -3e38f, -3e38f};
    #pragma unroll
    for (int tf = 0; tf < 13; ++tf) {
      const bool ok = (tf * 16 + fr) < 197;
      #pragma unroll
      for (int r = 0; r < 4; ++r) {
        float v = ok ? sc[tf][r] : -3e38f;
        sc[tf][r] = v;
        mx[r] = fmaxf(mx[r], v);
      }
    }
    #pragma unroll
    for (int r = 0; r < 4; ++r)
      #pragma unroll
      for (int d = 1; d < 16; d <<= 1) mx[r] = fmaxf(mx[r], __shfl_xor(mx[r], d));
    float sm[4] = {0.f, 0.f, 0.f, 0.f};
    #pragma unroll
    for (int tf = 0; tf < 13; ++tf) {
      #pragma unroll
      for (int r = 0; r < 4; ++r) {
        float e = __expf(sc[tf][r] - mx[r]);
        sm[r] += e;
        Pl[(fg * 4 + r) * SP2 + tf * 16 + fr] = f2bf(e);
      }
    }
    #pragma unroll
    for (int r = 0; r < 4; ++r) {
      #pragma unroll
      for (int d = 1; d < 16; d <<= 1) sm[r] += __shfl_xor(sm[r], d);
      if (fr == 0) sums[wave][fg * 4 + r] = sm[r];
    }
    #pragma unroll
    for (int r = 0; r < 4; ++r) Pl[(fg * 4 + r) * SP2 + 208 + fr] = 0;
    f32x4 o[4] = {};
    #pragma unroll
    for (int ks = 0; ks < 7; ++ks) {
      bf16x8 pf = ld16(Pl + fr * SP2 + ks * 32 + fg * 8);
      #pragma unroll
      for (int ef = 0; ef < 4; ++ef) {
        bf16x8 vf = ld16(Vb + (size_t)(ef * 16 + fr) * SP2 + ks * 32 + fg * 8);
        o[ef] = mfma16(vf, pf, o[ef]);
      }
    }
    const float inv = 1.f / sums[wave][fr];
    const int s = s0 + fr;
    if (s < 197) {
      float* xp = X + ((size_t)b * SEQL + s) * 768 + h * 64;
      #pragma unroll
      for (int ef = 0; ef < 4; ++ef)
        #pragma unroll
        for (int r = 0; r < 4; ++r)
          xp[ef * 16 + fg * 4 + r] += o[ef][r] * inv;
    }
  }
}

// ---------------- classifier head + softmax ----------------
__global__ __launch_bounds__(256) void head_kernel(const float* __restrict__ X,
    const float* __restrict__ hw, const float* __restrict__ hb, float* __restrict__ out) {
  __shared__ float xr[768];
  __shared__ float lg[1000];
  __shared__ float red[8];
  const int b = blockIdx.x, tid = threadIdx.x;
  for (int c = tid; c < 768; c += 256) xr[c] = X[(size_t)b * SEQL * 768 + c];
  __syncthreads();
  for (int n = tid; n < 1000; n += 256) {
    const F4* w4 = (const F4*)(hw + (size_t)n * 768);
    const F4* x4 = (const F4*)xr;
    float acc = hb[n];
    for (int k = 0; k < 192; ++k) {
      F4 w = w4[k]; F4 xv = x4[k];
      acc += w.x[0] * xv.x[0] + w.x[1] * xv.x[1] + w.x[2] * xv.x[2] + w.x[3] * xv.x[3];
    }
    lg[n] = acc;
  }
  __syncthreads();
  float m = -3e38f;
  for (int n = tid; n < 1000; n += 256) m = fmaxf(m, lg[n]);
  #pragma unroll
  for (int d = 1; d < 64; d <<= 1) m = fmaxf(m, __shfl_xor(m, d));
  if ((tid & 63) == 0) red[tid >> 6] = m;
  __syncthreads();
  m = fmaxf(fmaxf(red[0], red[1]), fmaxf(red[2], red[3]));
  float s = 0.f;
  for (int n = tid; n < 1000; n += 256) s += expf(lg[n] - m);
  #pragma unroll
  for (int d = 1; d < 64; d <<= 1) s += __shfl_xor(s, d);
  if ((tid & 63) == 0) red[4 + (tid >> 6)] = s;
  __syncthreads();
  s = red[4] + red[5] + red[6] + red[7];
  const float inv = 1.f / s;
  for (int n = tid; n < 1000; n += 256) out[(size_t)b * 1000 + n] = expf(lg[n] - m) * inv;
}

// ---------------- host launcher ----------------
extern "C" void kernel_launch(void* const* d_in, const int* in_sizes, int n_in,
                              void* d_out, int out_size, void* d_ws, size_t ws_size,
                              hipStream_t stream) {
  (void)in_sizes; (void)n_in; (void)out_size;
  if (ws_size < WS_SMALL) { printf("ws too small: %zu < %zu\n", ws_size, WS_SMALL); return; }
  const bool hoist = ws_size >= WS_BIG;

  const float* images   = (const float*)d_in[0];
  const float* mapper_w = (const float*)d_in[1];
  const float* mapper_b = (const float*)d_in[2];
  const float* cls_tok  = (const float*)d_in[3];
  const float* ln1_g    = (const float*)d_in[4];
  const float* ln1_b    = (const float*)d_in[5];
  const float* qw       = (const float*)d_in[6];
  const float* qb       = (const float*)d_in[7];
  const float* kw       = (const float*)d_in[8];
  const float* kb       = (const float*)d_in[9];
  const float* vw       = (const float*)d_in[10];
  const float* vb       = (const float*)d_in[11];
  const float* ln2_g    = (const float*)d_in[12];
  const float* ln2_b    = (const float*)d_in[13];
  const float* w1       = (const float*)d_in[14];
  const float* b1       = (const float*)d_in[15];
  const float* w2       = (const float*)d_in[16];
  const float* b2       = (const float*)d_in[17];
  const float* head_w   = (const float*)d_in[18];
  const float* head_b   = (const float*)d_in[19];

  char* ws = (char*)d_ws;
  float* X    = (float*)(ws + OFF_X);
  u16*  Aln   = (u16*)(ws + OFF_ALN);
  u16*  Hb    = (u16*)(ws + OFF_H);
  u16*  Wmap  = (u16*)(ws + OFF_WMAP);
  u16*  Qb    = (u16*)(ws + OFF_Q);
  u16*  Kb    = (u16*)(ws + OFF_K);
  u16*  Vtb   = (u16*)(ws + OFF_VT);
  u16*  Pat   = (u16*)(ws + OFF_PAT);
  float* Pos  = (float*)(ws + OFF_POS);
  u16*  WqA   = (u16*)(ws + OFF_WTS);
  u16*  W1A   = WqA + (size_t)(hoist ? 12 : 1) * QSZ;
  u16*  W2A   = W1A + (size_t)(hoist ? 12 : 1) * WSZ;

  // zero pads only: Q/K rows [197,208), Vt cols [197,224), X rows [MROWS,MPAD)
  padzero_kernel<<<(2 * BHN * 352 + BHN * 64 * 27 + 255) / 256, 256, 0, stream>>>(Qb, Kb, Vtb);
  zero_kernel<<<64, 256, 0, stream>>>((u32*)(X + (size_t)MROWS * 768), (long)((MPAD - MROWS) * 768));

  pos_kernel<<<(SEQL * 768 + 255) / 256, 256, 0, stream>>>(Pos);
  cvt_kernel<<<(768 * 768 + 255) / 256, 256, 0, stream>>>(mapper_w, Wmap, 768 * 768);
  patchify_kernel<<<(MPATCH * 768 + 255) / 256, 256, 0, stream>>>(images, Pat);
  cls_kernel<<<NB, 256, 0, stream>>>(cls_tok, Pos, X);

  if (hoist) {
    const int N_ALL = 12 * QSZ + 2 * 12 * (WSZ / 4);
    prep_all<<<(N_ALL + 255) / 256, 256, 0, stream>>>(qw, kw, vw, w1, w2, WqA, W1A, W2A);
  }

  // patch embedding: [12544 x 768] @ [768 x 768]^T -> X (with +bias +pos)
  gemm128<EPI_PATCH><<<(MPATCH / 128) * (768 / 128), 256, 0, stream>>>(
      Pat, Wmap, 768, 768, 768, MPATCH / 128, 768 / 128,
      mapper_b, nullptr, nullptr, X, Pos, nullptr, nullptr, nullptr);

  const int PREP_N = QSZ + 2 * (WSZ / 4);
  for (int blk = 0; blk < 12; ++blk) {
    u16* Wq_b = WqA + (size_t)(hoist ? blk : 0) * QSZ;
    u16* W1_b = W1A + (size_t)(hoist ? blk : 0) * WSZ;
    u16* W2_b = W2A + (size_t)(hoist ? blk : 0) * WSZ;
    ln_kernel<<<MPAD / 4, 256, 0, stream>>>(X, ln1_g + blk * 768, ln1_b + blk * 768, Aln);
    if (!hoist)
      prep_kernel<<<(PREP_N + 255) / 256, 256, 0, stream>>>(
          qw, kw, vw, w1, w2, Wq_b, W1_b, W2_b, blk);
    qkv_flat<<<768, 256, 0, stream>>>(
        Aln, Wq_b, qb + blk * 768, kb + blk * 768, vb + blk * 768,
        Qb, Kb, Vtb, (MPAD / 128) * 18, 768);
    attn_kernel<<<BHN, 256, 0, stream>>>(Qb, Kb, Vtb, X);
    ln_kernel<<<MPAD / 4, 256, 0, stream>>>(X, ln2_g + blk * 768, ln2_b + blk * 768, Aln);
    gemm128f_gelu<<<768, 256, 0, stream>>>(Aln, W1_b, b1 + blk * 3072, Hb, 2376, 768);
    gemm128<EPI_RESID><<<(MPAD / 128) * (768 / 128), 256, 0, stream>>>(
        Hb, W2_b, 3072, 3072, 3072, MPAD / 128, 768 / 128,
        b2 + blk * 768, nullptr, nullptr, X, nullptr, nullptr, nullptr, nullptr);
  }

  head_kernel<<<NB, 256, 0, stream>>>(X, head_w, head_b, (float*)d_out);
}

// Round 14
// 3955.835 us; speedup vs baseline: 1.2454x; 1.2454x over previous
//
#include <hip/hip_runtime.h>
#include <cstdint>
#include <cstddef>
#include <cstdio>

using u16 = unsigned short;
using u32 = unsigned int;

typedef __attribute__((ext_vector_type(8))) __bf16 bf16x8;
typedef __attribute__((ext_vector_type(4))) float f32x4;

struct alignas(16) U128 { u32 w[4]; };
struct alignas(16) F4   { float x[4]; };
struct alignas(8)  US4  { u16 h[4]; };

#define DEVFN static __device__ __forceinline__

DEVFN u16 f2bf(float x) {
  union { float f; u32 u; } v; v.f = x;
  u32 r = v.u + 0x7fffu + ((v.u >> 16) & 1u);
  return (u16)(r >> 16);
}

DEVFN bf16x8 ld16(const u16* p) { return __builtin_bit_cast(bf16x8, *(const U128*)p); }

DEVFN f32x4 mfma16(bf16x8 a, bf16x8 b, f32x4 c) {
  return __builtin_amdgcn_mfma_f32_16x16x32_bf16(a, b, c, 0, 0, 0);
}

DEVFN void gload_lds16(const u16* g, u16* l) {
  __builtin_amdgcn_global_load_lds(
      (const __attribute__((address_space(1))) void*)g,
      (__attribute__((address_space(3))) void*)l, 16, 0, 0);
}

// fast gelu (exact erf via A&S 7.1.26, |err| <= 1.5e-7)
DEVFN float gelu(float x) {
  float z = fabsf(x) * 0.70710678118f;
  float t = __builtin_amdgcn_rcpf(1.f + 0.3275911f * z);
  float p = t * (0.254829592f + t * (-0.284496736f + t * (1.421413741f +
            t * (-1.453152027f + t * 1.061405429f))));
  float e = __expf(-z * z);
  float erfz = 1.f - p * e;
  erfz = copysignf(erfz, x);
  return 0.5f * x * (1.f + erfz);
}

// A-panel-locality dispatch remap (stride-8 preserves XCD; halved FETCH, R5).
DEVFN void remap_bid(int bid, int Mb, int Nb, int& bm, int& bn) {
  const int ngrp  = Mb >> 3;
  const int per   = Nb << 3;
  const int nfull = ngrp * per;
  if (bid < nfull) {
    const int bmg = bid / per;
    const int rem = bid - bmg * per;
    bn = rem >> 3;
    bm = (bmg << 3) + (rem & 7);
  } else {
    const int r = bid - nfull;
    const int q = r / Nb;
    bm = (ngrp << 3) + q;
    bn = r - q * Nb;
  }
}

// ---------------- dimensions ----------------
constexpr int SEQL   = 197;
constexpr int NB     = 64;
constexpr int NH     = 12;
constexpr int MROWS  = NB * SEQL;    // 12608 real rows
constexpr int MPAD   = 12672;        // 99 * 128
constexpr int MPAD2  = 12800;        // buffer sizing
constexpr int MPATCH = NB * 196;     // 12544
constexpr int SP     = 208;          // padded seq for Q/K (13*16)
constexpr int SP2    = 224;          // padded seq for Vt / P (7*32)
constexpr int BHN    = NB * NH;      // 768 (b,h) pairs

constexpr int QSZ    = 2304 * 128;   // per-block Wqkv elems
constexpr int WSZ    = 3072 * 768;   // per-block W1/W2 elems

// ---------------- workspace layout (bytes) ----------------
constexpr size_t OFF_X    = 0;                                          // fp32 residual [MPAD][768]
constexpr size_t OFF_ALN  = OFF_X    + (size_t)MPAD * 768 * 4;          // bf16 LN out  [MPAD2][768]
constexpr size_t OFF_H    = OFF_ALN  + (size_t)MPAD2 * 768 * 2;         // bf16 mlp mid [MPAD2][3072]
constexpr size_t OFF_WMAP = OFF_H    + (size_t)MPAD2 * 3072 * 2;        // bf16 [768][768]
constexpr size_t OFF_Q    = OFF_WMAP + (size_t)768 * 768 * 2;           // bf16 [BHN][SP][64]
constexpr size_t OFF_K    = OFF_Q    + (size_t)BHN * SP * 64 * 2;
constexpr size_t OFF_VT   = OFF_K    + (size_t)BHN * SP * 64 * 2;       // bf16 [BHN][64][SP2]
constexpr size_t OFF_PAT  = OFF_VT   + (size_t)BHN * 64 * SP2 * 2;      // bf16 [12544][768]
constexpr size_t OFF_POS  = OFF_PAT  + (size_t)MPATCH * 768 * 2;        // fp32 [197][768]
constexpr size_t OFF_WTS  = OFF_POS  + (size_t)SEQL * 768 * 4;          // bf16 weights
constexpr size_t WS_SMALL = OFF_WTS + (size_t)(QSZ + 2 * WSZ) * 2;      // 1-block slots
constexpr size_t WS_BIG   = OFF_WTS + (size_t)12 * (QSZ + 2 * WSZ) * 2; // all 12 hoisted

// ---------------- small utility kernels ----------------
__global__ void zero_kernel(u32* __restrict__ p, long n) {
  long i = (long)blockIdx.x * 256 + threadIdx.x;
  long stride = (long)gridDim.x * 256;
  for (; i < n; i += stride) p[i] = 0u;
}

// zero only the pad regions of Q/K (rows 197..207) and Vt (cols 197..223)
__global__ void padzero_kernel(u16* __restrict__ Q, u16* __restrict__ Kp,
                               u16* __restrict__ Vt) {
  const int NQ32 = BHN * 352;          // 11 rows * 64 e / 2 per bh
  const int NV   = BHN * 64 * 27;
  int i = blockIdx.x * 256 + threadIdx.x;
  if (i < NQ32) {
    int bh = i / 352, r = i - bh * 352;
    ((u32*)(Q + ((size_t)bh * SP + 197) * 64))[r] = 0u;
  } else if (i < 2 * NQ32) {
    int j = i - NQ32;
    int bh = j / 352, r = j - bh * 352;
    ((u32*)(Kp + ((size_t)bh * SP + 197) * 64))[r] = 0u;
  } else if (i < 2 * NQ32 + NV) {
    int j = i - 2 * NQ32;
    int be = j / 27, s = j - be * 27;
    Vt[(size_t)be * SP2 + 197 + s] = 0;
  }
}

__global__ void cvt_kernel(const float* __restrict__ src, u16* __restrict__ dst, int n) {
  int i = blockIdx.x * 256 + threadIdx.x;
  if (i < n) dst[i] = f2bf(src[i]);
}

__global__ void pos_kernel(float* __restrict__ pos) {
  int i = blockIdx.x * 256 + threadIdx.x;
  if (i >= SEQL * 768) return;
  int s = i / 768, j = i - s * 768;
  float expo = (float)(j & ~1) * (1.0f / 768.0f);
  float ang  = (float)s * expf(-expo * logf(10000.0f));
  pos[i] = (j & 1) ? cosf(ang) : sinf(ang);
}

__global__ void cls_kernel(const float* __restrict__ cls, const float* __restrict__ pos,
                           float* __restrict__ X) {
  int b = blockIdx.x;
  for (int c = threadIdx.x; c < 768; c += 256)
    X[(size_t)b * SEQL * 768 + c] = cls[c] + pos[c];
}

__global__ void patchify_kernel(const float* __restrict__ img, u16* __restrict__ out) {
  int i = blockIdx.x * 256 + threadIdx.x;
  if (i >= MPATCH * 768) return;
  int m = i / 768, k = i - m * 768;
  int b = m / 196, p = m - b * 196;
  int py = p / 14, px = p - py * 14;
  int c = k >> 8, rem = k & 255, iy = rem >> 4, ix = rem & 15;
  float v = img[(((size_t)b * 3 + c) * 224 + py * 16 + iy) * 224 + px * 16 + ix];
  out[i] = f2bf(v);
}

// hoisted prep: ALL 12 blocks' Wqkv + W1 + W2 -> bf16 in one launch
__global__ void prep_all(const float* __restrict__ qw, const float* __restrict__ kw,
                         const float* __restrict__ vw, const float* __restrict__ w1,
                         const float* __restrict__ w2,
                         u16* __restrict__ Wq, u16* __restrict__ W1b,
                         u16* __restrict__ W2b) {
  const int NQ = 12 * QSZ;
  const int NV = 12 * (WSZ / 4);
  int i = blockIdx.x * 256 + threadIdx.x;
  if (i < NQ) {
    int blk = i / QSZ;
    int r = i - blk * QSZ;
    int n = r >> 7, kk = r & 127;
    int p = n / 768, ef = n - p * 768;
    int h = ef >> 6, e = ef & 63;
    float v = 0.f;
    if ((kk >> 6) == (h & 1)) {
      int d = kk & 63;
      const float* w = (p == 0) ? qw : (p == 1) ? kw : vw;
      v = w[(((size_t)blk * NH + h) * 64 + e) * 64 + d];
    }
    Wq[i] = f2bf(v);
  } else if (i < NQ + NV) {
    int j = (i - NQ) * 4;
    F4 v = *(const F4*)(w1 + j);
    US4 o;
    #pragma unroll
    for (int r = 0; r < 4; ++r) o.h[r] = f2bf(v.x[r]);
    *(US4*)(W1b + j) = o;
  } else if (i < NQ + 2 * NV) {
    int j = (i - NQ - NV) * 4;
    F4 v = *(const F4*)(w2 + j);
    US4 o;
    #pragma unroll
    for (int r = 0; r < 4; ++r) o.h[r] = f2bf(v.x[r]);
    *(US4*)(W2b + j) = o;
  }
}

// fallback per-block prep (small-ws path)
__global__ void prep_kernel(const float* __restrict__ qw, const float* __restrict__ kw,
                            const float* __restrict__ vw, const float* __restrict__ w1,
                            const float* __restrict__ w2,
                            u16* __restrict__ Wqkv, u16* __restrict__ W1b,
                            u16* __restrict__ W2b, int blk) {
  const int NV = WSZ / 4;
  int i = blockIdx.x * 256 + threadIdx.x;
  if (i < QSZ) {
    int n = i >> 7, kk = i & 127;
    int p = n / 768, ef = n - p * 768;
    int h = ef >> 6, e = ef & 63;
    float v = 0.f;
    if ((kk >> 6) == (h & 1)) {
      int d = kk & 63;
      const float* w = (p == 0) ? qw : (p == 1) ? kw : vw;
      v = w[(((size_t)blk * NH + h) * 64 + e) * 64 + d];
    }
    Wqkv[i] = f2bf(v);
  } else if (i < QSZ + NV) {
    int j = (i - QSZ) * 4;
    F4 v = *(const F4*)(w1 + (size_t)blk * WSZ + j);
    US4 o;
    #pragma unroll
    for (int r = 0; r < 4; ++r) o.h[r] = f2bf(v.x[r]);
    *(US4*)(W1b + j) = o;
  } else if (i < QSZ + 2 * NV) {
    int j = (i - QSZ - NV) * 4;
    F4 v = *(const F4*)(w2 + (size_t)blk * WSZ + j);
    US4 o;
    #pragma unroll
    for (int r = 0; r < 4; ++r) o.h[r] = f2bf(v.x[r]);
    *(US4*)(W2b + j) = o;
  }
}

// ---------------- layernorm: fp32 row -> bf16 row ----------------
__global__ __launch_bounds__(256) void ln_kernel(const float* __restrict__ X,
    const float* __restrict__ g, const float* __restrict__ b, u16* __restrict__ out) {
  int row  = blockIdx.x * 4 + (threadIdx.x >> 6);
  int lane = threadIdx.x & 63;
  const float* x = X + (size_t)row * 768 + lane * 12;
  F4 a0 = *(const F4*)(x);
  F4 a1 = *(const F4*)(x + 4);
  F4 a2 = *(const F4*)(x + 8);
  float v[12];
  #pragma unroll
  for (int j = 0; j < 4; ++j) { v[j] = a0.x[j]; v[4 + j] = a1.x[j]; v[8 + j] = a2.x[j]; }
  float s = 0.f, q = 0.f;
  #pragma unroll
  for (int j = 0; j < 12; ++j) { s += v[j]; q += v[j] * v[j]; }
  #pragma unroll
  for (int d = 1; d < 64; d <<= 1) { s += __shfl_xor(s, d); q += __shfl_xor(q, d); }
  float mu  = s * (1.f / 768.f);
  float var = q * (1.f / 768.f) - mu * mu;
  float rs  = rsqrtf(var + 1e-5f);
  const float* gp = g + lane * 12;
  const float* bp = b + lane * 12;
  u16* op = out + (size_t)row * 768 + lane * 12;
  u16 o[12];
  #pragma unroll
  for (int j = 0; j < 12; ++j) o[j] = f2bf((v[j] - mu) * rs * gp[j] + bp[j]);
  #pragma unroll
  for (int c = 0; c < 3; ++c) {
    US4 w; w.h[0] = o[c*4]; w.h[1] = o[c*4+1]; w.h[2] = o[c*4+2]; w.h[3] = o[c*4+3];
    *(US4*)(op + c * 4) = w;
  }
}

enum { EPI_PATCH = 0, EPI_QKV = 1, EPI_GELU = 2, EPI_RESID = 3 };

// ========== unified 128x128 BK=32 4-wave GEMM, TRIPLE-buffered, counted vmcnt ======
// (r8/r10 proven structure — used for PATCH and RESID.)
template<int EPI>
__global__ __launch_bounds__(256, 3) void gemm128(
    const u16* __restrict__ A, const u16* __restrict__ B, int K, int lda, int ldb,
    int Mb, int Nb,
    const float* __restrict__ e0, const float* __restrict__ e1, const float* __restrict__ e2,
    float* __restrict__ f0, const float* __restrict__ f1,
    u16* __restrict__ o0, u16* __restrict__ o1, u16* __restrict__ o2) {
  __shared__ u16 Ab[3][128 * 32];
  __shared__ u16 Bb[3][128 * 32];
  const int tid  = threadIdx.x;
  const int wave = tid >> 6, lane = tid & 63;
  int bm, bn;
  remap_bid(blockIdx.x, Mb, Nb, bm, bn);
  const int fr = lane & 15, fg = lane >> 4;
  const int srow = wave * 16 + (lane >> 2);
  const int gcol = ((lane & 3) ^ ((lane >> 3) & 3)) * 8;
  const u16* gA = A + (size_t)(bm * 128 + srow) * lda + gcol;
  const u16* gB = B + (size_t)(bn * 128 + srow) * ldb + gcol;
  const int wm = (wave >> 1) * 64, wn = (wave & 1) * 64;
  const int sl = (fg ^ ((fr >> 1) & 3)) * 8;
  const int nt = K >> 5;

  auto STAGE = [&](int c, int t) {
    gload_lds16(gA + t * 32,                    &Ab[c][0] + wave * 512);
    gload_lds16(gA + t * 32 + (size_t)64 * lda, &Ab[c][0] + wave * 512 + 2048);
    gload_lds16(gB + t * 32,                    &Bb[c][0] + wave * 512);
    gload_lds16(gB + t * 32 + (size_t)64 * ldb, &Bb[c][0] + wave * 512 + 2048);
  };

  f32x4 acc[4][4] = {};
  STAGE(0, 0);
  if (nt > 1) STAGE(1, 1);
  int bi = 0;
  for (int t = 0; t < nt; ++t) {
    if (t + 1 < nt) asm volatile("s_waitcnt vmcnt(4)" ::: "memory");
    else            asm volatile("s_waitcnt vmcnt(0)" ::: "memory");
    __builtin_amdgcn_s_barrier();
    if (t + 2 < nt) { int si = bi + 2; if (si >= 3) si -= 3; STAGE(si, t + 2); }
    const u16* ab   = &Ab[bi][0];
    const u16* bbuf = &Bb[bi][0];
    bf16x8 af[4], bfv[4];
    #pragma unroll
    for (int i = 0; i < 4; ++i) af[i]  = ld16(ab + (wm + i * 16 + fr) * 32 + sl);
    #pragma unroll
    for (int j = 0; j < 4; ++j) bfv[j] = ld16(bbuf + (wn + j * 16 + fr) * 32 + sl);
    __builtin_amdgcn_s_setprio(1);
    #pragma unroll
    for (int i = 0; i < 4; ++i)
      #pragma unroll
      for (int j = 0; j < 4; ++j)
        acc[i][j] = mfma16(af[i], bfv[j], acc[i][j]);
    __builtin_amdgcn_s_setprio(0);
    bi = (bi + 1 == 3) ? 0 : bi + 1;
  }

  // epilogue: C frag col = fr, row = fg*4 + r
  #pragma unroll
  for (int i = 0; i < 4; ++i) {
    #pragma unroll
    for (int r = 0; r < 4; ++r) {
      const int m = bm * 128 + wm + i * 16 + fg * 4 + r;
      if constexpr (EPI == EPI_PATCH) {
        const int bb = m / 196;
        const int s  = m - bb * 196 + 1;
        float* xrow = f0 + ((size_t)bb * SEQL + s) * 768;
        const float* prow = f1 + (size_t)s * 768;
        #pragma unroll
        for (int j = 0; j < 4; ++j) {
          const int n = bn * 128 + wn + j * 16 + fr;
          xrow[n] = acc[i][j][r] + e0[n] + prow[n];
        }
      } else { // EPI_RESID
        if (m < MROWS) {
          float* xrow = f0 + (size_t)m * 768;
          #pragma unroll
          for (int j = 0; j < 4; ++j) {
            const int n = bn * 128 + wn + j * 16 + fr;
            xrow[n] += acc[i][j][r] + e0[n];
          }
        }
      }
    }
  }
}

// ========== persistent/flattened GELU GEMM (M=12672, N=3072, K=768) ==============
__global__ __launch_bounds__(256, 3) void gemm128f_gelu(
    const u16* __restrict__ A, const u16* __restrict__ B,
    const float* __restrict__ e0, u16* __restrict__ o0,
    int ntiles, int nblocks) {
  __shared__ u16 Ab[3][128 * 32];
  __shared__ u16 Bb[3][128 * 32];
  constexpr int lda = 768, ldb = 768, nt = 24;   // K = 768
  const int tid = threadIdx.x, wave = tid >> 6, lane = tid & 63;
  const int fr = lane & 15, fg = lane >> 4;
  const int srow = wave * 16 + (lane >> 2);
  const int gcol = ((lane & 3) ^ ((lane >> 3) & 3)) * 8;
  const int wm = (wave >> 1) * 64, wn = (wave & 1) * 64;
  const int sl = (fg ^ ((fr >> 1) & 3)) * 8;
  const int myTiles = (ntiles - (int)blockIdx.x + nblocks - 1) / nblocks;
  const int total = myTiles * nt;

  int s_t  = blockIdx.x;
  int s_kk = 0;
  const u16 *s_gA, *s_gB;
  {
    int bm, bn; remap_bid(s_t, 99, 24, bm, bn);
    s_gA = A + (size_t)(bm * 128 + srow) * lda + gcol;
    s_gB = B + (size_t)(bn * 128 + srow) * ldb + gcol;
  }
  auto STAGE1 = [&](int c) {
    gload_lds16(s_gA + s_kk * 32,                    &Ab[c][0] + wave * 512);
    gload_lds16(s_gA + s_kk * 32 + (size_t)64 * lda, &Ab[c][0] + wave * 512 + 2048);
    gload_lds16(s_gB + s_kk * 32,                    &Bb[c][0] + wave * 512);
    gload_lds16(s_gB + s_kk * 32 + (size_t)64 * ldb, &Bb[c][0] + wave * 512 + 2048);
    if (++s_kk == nt) {
      s_kk = 0;
      s_t += nblocks;
      if (s_t < ntiles) {
        int bm, bn; remap_bid(s_t, 99, 24, bm, bn);
        s_gA = A + (size_t)(bm * 128 + srow) * lda + gcol;
        s_gB = B + (size_t)(bn * 128 + srow) * ldb + gcol;
      }
    }
  };

  STAGE1(0);
  if (total > 1) STAGE1(1);
  int bi = 0, g = 0;
  for (int t = blockIdx.x; t < ntiles; t += nblocks) {
    int bm, bn; remap_bid(t, 99, 24, bm, bn);
    f32x4 acc[4][4] = {};
    for (int k = 0; k < nt; ++k, ++g) {
      if (g + 1 < total) asm volatile("s_waitcnt vmcnt(4)" ::: "memory");
      else               asm volatile("s_waitcnt vmcnt(0)" ::: "memory");
      __builtin_amdgcn_s_barrier();
      if (g + 2 < total) { int si = bi + 2; if (si >= 3) si -= 3; STAGE1(si); }
      const u16* ab   = &Ab[bi][0];
      const u16* bbuf = &Bb[bi][0];
      bf16x8 af[4], bfv[4];
      #pragma unroll
      for (int i = 0; i < 4; ++i) af[i]  = ld16(ab + (wm + i * 16 + fr) * 32 + sl);
      #pragma unroll
      for (int j = 0; j < 4; ++j) bfv[j] = ld16(bbuf + (wn + j * 16 + fr) * 32 + sl);
      __builtin_amdgcn_s_setprio(1);
      #pragma unroll
      for (int i = 0; i < 4; ++i)
        #pragma unroll
        for (int j = 0; j < 4; ++j)
          acc[i][j] = mfma16(af[i], bfv[j], acc[i][j]);
      __builtin_amdgcn_s_setprio(0);
      bi = (bi + 1 == 3) ? 0 : bi + 1;
    }
    // epilogue (GELU)
    #pragma unroll
    for (int i = 0; i < 4; ++i) {
      #pragma unroll
      for (int r = 0; r < 4; ++r) {
        const int m = bm * 128 + wm + i * 16 + fg * 4 + r;
        u16* hrow = o0 + (size_t)m * 3072;
        #pragma unroll
        for (int j = 0; j < 4; ++j) {
          const int n = bn * 128 + wn + j * 16 + fr;
          hrow[n] = f2bf(gelu(acc[i][j][r] + e0[n]));
        }
      }
    }
  }
}

// ========== persistent/flattened QKV GEMM (M=12672, N=2304 compact-K=128) ==========
__global__ __launch_bounds__(256, 3) void qkv_flat(
    const u16* __restrict__ A, const u16* __restrict__ B,
    const float* __restrict__ e0, const float* __restrict__ e1, const float* __restrict__ e2,
    u16* __restrict__ o0, u16* __restrict__ o1, u16* __restrict__ o2,
    int ntiles, int nblocks) {
  __shared__ u16 Ab[3][128 * 32];
  __shared__ u16 Bb[3][128 * 32];
  constexpr int lda = 768, ldb = 128, nt = 4;   // compact K = 128
  const int tid = threadIdx.x, wave = tid >> 6, lane = tid & 63;
  const int fr = lane & 15, fg = lane >> 4;
  const int srow = wave * 16 + (lane >> 2);
  const int gcol = ((lane & 3) ^ ((lane >> 3) & 3)) * 8;
  const int wm = (wave >> 1) * 64, wn = (wave & 1) * 64;
  const int sl = (fg ^ ((fr >> 1) & 3)) * 8;
  const int myTiles = (ntiles - (int)blockIdx.x + nblocks - 1) / nblocks;
  if (myTiles <= 0) return;
  const int total = myTiles * nt;

  int s_t  = blockIdx.x;
  int s_kk = 0;
  const u16 *s_gA, *s_gB;
  {
    int bm, bn; remap_bid(s_t, 99, 18, bm, bn);
    s_gA = A + (bn % 6) * 128 + (size_t)(bm * 128 + srow) * lda + gcol;
    s_gB = B + (size_t)(bn * 128 + srow) * ldb + gcol;
  }
  auto STAGE1 = [&](int c) {
    gload_lds16(s_gA + s_kk * 32,                    &Ab[c][0] + wave * 512);
    gload_lds16(s_gA + s_kk * 32 + (size_t)64 * lda, &Ab[c][0] + wave * 512 + 2048);
    gload_lds16(s_gB + s_kk * 32,                    &Bb[c][0] + wave * 512);
    gload_lds16(s_gB + s_kk * 32 + (size_t)64 * ldb, &Bb[c][0] + wave * 512 + 2048);
    if (++s_kk == nt) {
      s_kk = 0;
      s_t += nblocks;
      if (s_t < ntiles) {
        int bm, bn; remap_bid(s_t, 99, 18, bm, bn);
        s_gA = A + (bn % 6) * 128 + (size_t)(bm * 128 + srow) * lda + gcol;
        s_gB = B + (size_t)(bn * 128 + srow) * ldb + gcol;
      }
    }
  };

  STAGE1(0);
  if (total > 1) STAGE1(1);
  int bi = 0, g = 0;
  for (int t = blockIdx.x; t < ntiles; t += nblocks) {
    int bm, bn; remap_bid(t, 99, 18, bm, bn);
    f32x4 acc[4][4] = {};
    #pragma unroll
    for (int k = 0; k < nt; ++k, ++g) {
      if (g + 1 < total) asm volatile("s_waitcnt vmcnt(4)" ::: "memory");
      else               asm volatile("s_waitcnt vmcnt(0)" ::: "memory");
      __builtin_amdgcn_s_barrier();
      if (g + 2 < total) { int si = bi + 2; if (si >= 3) si -= 3; STAGE1(si); }
      const u16* ab   = &Ab[bi][0];
      const u16* bbuf = &Bb[bi][0];
      bf16x8 af[4], bfv[4];
      #pragma unroll
      for (int i = 0; i < 4; ++i) af[i]  = ld16(ab + (wm + i * 16 + fr) * 32 + sl);
      #pragma unroll
      for (int j = 0; j < 4; ++j) bfv[j] = ld16(bbuf + (wn + j * 16 + fr) * 32 + sl);
      __builtin_amdgcn_s_setprio(1);
      #pragma unroll
      for (int i = 0; i < 4; ++i)
        #pragma unroll
        for (int j = 0; j < 4; ++j)
          acc[i][j] = mfma16(af[i], bfv[j], acc[i][j]);
      __builtin_amdgcn_s_setprio(0);
      bi = (bi + 1 == 3) ? 0 : bi + 1;
    }
    // epilogue (QKV scatter)
    #pragma unroll
    for (int i = 0; i < 4; ++i) {
      #pragma unroll
      for (int r = 0; r < 4; ++r) {
        const int m = bm * 128 + wm + i * 16 + fg * 4 + r;
        if (m < MROWS) {
          const int bb = m / 197;
          const int s  = m - bb * 197;
          #pragma unroll
          for (int j = 0; j < 4; ++j) {
            const int n = bn * 128 + wn + j * 16 + fr;
            const int p = n / 768;
            const int ef = n - p * 768;
            const int h = ef >> 6, e = ef & 63;
            const size_t bh = (size_t)bb * NH + h;
            if (p == 0)      o0[(bh * SP + s) * 64 + e] = f2bf((acc[i][j][r] + e0[ef]) * 0.125f);
            else if (p == 1) o1[(bh * SP + s) * 64 + e] = f2bf(acc[i][j][r] + e1[ef]);
            else             o2[(bh * 64 + e) * SP2 + s] = f2bf(acc[i][j][r] + e2[ef]);
          }
        }
      }
    }
  }
}

// ---------------- fused attention: one block per (b,h); K staged in LDS ----------------
// (r12 measured-best: Kl staging is REQUIRED — r13 showed dropping it thrashes
// the per-XCD L2 at full concurrency: FETCH 15->228 MB, attn 15->121 us.)
__global__ __launch_bounds__(256, 2) void attn_kernel(const u16* __restrict__ Q,
    const u16* __restrict__ Km, const u16* __restrict__ Vt, float* __restrict__ X) {
  __shared__ u16  P[4][16 * SP2];      // 28 KB
  __shared__ u16  Kl[208 * 72];        // 29.25 KB, +8 pad -> conflict-free b128
  __shared__ float sums[4][16];
  const int bh = blockIdx.x;
  const int b = bh / NH, h = bh - b * NH;
  const int wave = threadIdx.x >> 6, lane = threadIdx.x & 63;
  const int fr = lane & 15, fg = lane >> 4;
  const u16* Qb = Q  + (size_t)bh * SP * 64;
  const u16* Kb = Km + (size_t)bh * SP * 64;
  const u16* Vb = Vt + (size_t)bh * 64 * SP2;
  {
    const int r0 = threadIdx.x >> 2;
    const int e  = (threadIdx.x & 3) * 16;
    #pragma unroll
    for (int rr = r0; rr < 208; rr += 64)
      *(U128*)(Kl + rr * 72 + e) = *(const U128*)(Kb + (size_t)rr * 64 + e);
  }
  __syncthreads();
  u16* Pl = &P[wave][0];
  for (int qt = wave; qt < 13; qt += 4) {
    const int s0 = qt * 16;
    bf16x8 qf0 = ld16(Qb + (size_t)(s0 + fr) * 64 + fg * 8);
    bf16x8 qf1 = ld16(Qb + (size_t)(s0 + fr) * 64 + 32 + fg * 8);
    f32x4 sc[13];
    #pragma unroll
    for (int tf = 0; tf < 13; ++tf) {
      f32x4 a = {0.f, 0.f, 0.f, 0.f};
      bf16x8 k0 = ld16(Kl + (tf * 16 + fr) * 72 + fg * 8);
      bf16x8 k1 = ld16(Kl + (tf * 16 + fr) * 72 + 32 + fg * 8);
      a = mfma16(qf0, k0, a);
      a = mfma16(qf1, k1, a);
      sc[tf] = a;
    }
    float mx[4] = {-3e38f, -3e38f, -3e38f, -3e38f};
    #pragma unroll
    for (int tf = 0; tf < 13; ++tf) {
      const bool ok = (tf * 16 + fr) < 197;
      #pragma unroll
      for (int r = 0; r < 4; ++r) {
        float v = ok ? sc[tf][r] : -3e38f;
        sc[tf][r] = v;
        mx[r] = fmaxf(mx[r], v);
      }
    }
    #pragma unroll
    for (int r = 0; r < 4; ++r)
      #pragma unroll
      for (int d = 1; d < 16; d <<= 1) mx[r] = fmaxf(mx[r], __shfl_xor(mx[r], d));
    float sm[4] = {0.f, 0.f, 0.f, 0.f};
    #pragma unroll
    for (int tf = 0; tf < 13; ++tf) {
      #pragma unroll
      for (int r = 0; r < 4; ++r) {
        float e = __expf(sc[tf][r] - mx[r]);
        sm[r] += e;
        Pl[(fg * 4 + r) * SP2 + tf * 16 + fr] = f2bf(e);
      }
    }
    #pragma unroll
    for (int r = 0; r < 4; ++r) {
      #pragma unroll
      for (int d = 1; d < 16; d <<= 1) sm[r] += __shfl_xor(sm[r], d);
      if (fr == 0) sums[wave][fg * 4 + r] = sm[r];
    }
    #pragma unroll
    for (int r = 0; r < 4; ++r) Pl[(fg * 4 + r) * SP2 + 208 + fr] = 0;
    f32x4 o[4] = {};
    #pragma unroll
    for (int ks = 0; ks < 7; ++ks) {
      bf16x8 pf = ld16(Pl + fr * SP2 + ks * 32 + fg * 8);
      #pragma unroll
      for (int ef = 0; ef < 4; ++ef) {
        bf16x8 vf = ld16(Vb + (size_t)(ef * 16 + fr) * SP2 + ks * 32 + fg * 8);
        o[ef] = mfma16(vf, pf, o[ef]);
      }
    }
    const float inv = 1.f / sums[wave][fr];
    const int s = s0 + fr;
    if (s < 197) {
      float* xp = X + ((size_t)b * SEQL + s) * 768 + h * 64;
      #pragma unroll
      for (int ef = 0; ef < 4; ++ef)
        #pragma unroll
        for (int r = 0; r < 4; ++r)
          xp[ef * 16 + fg * 4 + r] += o[ef][r] * inv;
    }
  }
}

// ---------------- classifier head + softmax ----------------
__global__ __launch_bounds__(256) void head_kernel(const float* __restrict__ X,
    const float* __restrict__ hw, const float* __restrict__ hb, float* __restrict__ out) {
  __shared__ float xr[768];
  __shared__ float lg[1000];
  __shared__ float red[8];
  const int b = blockIdx.x, tid = threadIdx.x;
  for (int c = tid; c < 768; c += 256) xr[c] = X[(size_t)b * SEQL * 768 + c];
  __syncthreads();
  for (int n = tid; n < 1000; n += 256) {
    const F4* w4 = (const F4*)(hw + (size_t)n * 768);
    const F4* x4 = (const F4*)xr;
    float acc = hb[n];
    for (int k = 0; k < 192; ++k) {
      F4 w = w4[k]; F4 xv = x4[k];
      acc += w.x[0] * xv.x[0] + w.x[1] * xv.x[1] + w.x[2] * xv.x[2] + w.x[3] * xv.x[3];
    }
    lg[n] = acc;
  }
  __syncthreads();
  float m = -3e38f;
  for (int n = tid; n < 1000; n += 256) m = fmaxf(m, lg[n]);
  #pragma unroll
  for (int d = 1; d < 64; d <<= 1) m = fmaxf(m, __shfl_xor(m, d));
  if ((tid & 63) == 0) red[tid >> 6] = m;
  __syncthreads();
  m = fmaxf(fmaxf(red[0], red[1]), fmaxf(red[2], red[3]));
  float s = 0.f;
  for (int n = tid; n < 1000; n += 256) s += expf(lg[n] - m);
  #pragma unroll
  for (int d = 1; d < 64; d <<= 1) s += __shfl_xor(s, d);
  if ((tid & 63) == 0) red[4 + (tid >> 6)] = s;
  __syncthreads();
  s = red[4] + red[5] + red[6] + red[7];
  const float inv = 1.f / s;
  for (int n = tid; n < 1000; n += 256) out[(size_t)b * 1000 + n] = expf(lg[n] - m) * inv;
}

// ---------------- host launcher ----------------
extern "C" void kernel_launch(void* const* d_in, const int* in_sizes, int n_in,
                              void* d_out, int out_size, void* d_ws, size_t ws_size,
                              hipStream_t stream) {
  (void)in_sizes; (void)n_in; (void)out_size;
  if (ws_size < WS_SMALL) { printf("ws too small: %zu < %zu\n", ws_size, WS_SMALL); return; }
  const bool hoist = ws_size >= WS_BIG;

  const float* images   = (const float*)d_in[0];
  const float* mapper_w = (const float*)d_in[1];
  const float* mapper_b = (const float*)d_in[2];
  const float* cls_tok  = (const float*)d_in[3];
  const float* ln1_g    = (const float*)d_in[4];
  const float* ln1_b    = (const float*)d_in[5];
  const float* qw       = (const float*)d_in[6];
  const float* qb       = (const float*)d_in[7];
  const float* kw       = (const float*)d_in[8];
  const float* kb       = (const float*)d_in[9];
  const float* vw       = (const float*)d_in[10];
  const float* vb       = (const float*)d_in[11];
  const float* ln2_g    = (const float*)d_in[12];
  const float* ln2_b    = (const float*)d_in[13];
  const float* w1       = (const float*)d_in[14];
  const float* b1       = (const float*)d_in[15];
  const float* w2       = (const float*)d_in[16];
  const float* b2       = (const float*)d_in[17];
  const float* head_w   = (const float*)d_in[18];
  const float* head_b   = (const float*)d_in[19];

  char* ws = (char*)d_ws;
  float* X    = (float*)(ws + OFF_X);
  u16*  Aln   = (u16*)(ws + OFF_ALN);
  u16*  Hb    = (u16*)(ws + OFF_H);
  u16*  Wmap  = (u16*)(ws + OFF_WMAP);
  u16*  Qb    = (u16*)(ws + OFF_Q);
  u16*  Kb    = (u16*)(ws + OFF_K);
  u16*  Vtb   = (u16*)(ws + OFF_VT);
  u16*  Pat   = (u16*)(ws + OFF_PAT);
  float* Pos  = (float*)(ws + OFF_POS);
  u16*  WqA   = (u16*)(ws + OFF_WTS);
  u16*  W1A   = WqA + (size_t)(hoist ? 12 : 1) * QSZ;
  u16*  W2A   = W1A + (size_t)(hoist ? 12 : 1) * WSZ;

  // zero pads only: Q/K rows [197,208), Vt cols [197,224), X rows [MROWS,MPAD)
  padzero_kernel<<<(2 * BHN * 352 + BHN * 64 * 27 + 255) / 256, 256, 0, stream>>>(Qb, Kb, Vtb);
  zero_kernel<<<64, 256, 0, stream>>>((u32*)(X + (size_t)MROWS * 768), (long)((MPAD - MROWS) * 768));

  pos_kernel<<<(SEQL * 768 + 255) / 256, 256, 0, stream>>>(Pos);
  cvt_kernel<<<(768 * 768 + 255) / 256, 256, 0, stream>>>(mapper_w, Wmap, 768 * 768);
  patchify_kernel<<<(MPATCH * 768 + 255) / 256, 256, 0, stream>>>(images, Pat);
  cls_kernel<<<NB, 256, 0, stream>>>(cls_tok, Pos, X);

  if (hoist) {
    const int N_ALL = 12 * QSZ + 2 * 12 * (WSZ / 4);
    prep_all<<<(N_ALL + 255) / 256, 256, 0, stream>>>(qw, kw, vw, w1, w2, WqA, W1A, W2A);
  }

  // patch embedding: [12544 x 768] @ [768 x 768]^T -> X (with +bias +pos)
  gemm128<EPI_PATCH><<<(MPATCH / 128) * (768 / 128), 256, 0, stream>>>(
      Pat, Wmap, 768, 768, 768, MPATCH / 128, 768 / 128,
      mapper_b, nullptr, nullptr, X, Pos, nullptr, nullptr, nullptr);

  const int PREP_N = QSZ + 2 * (WSZ / 4);
  for (int blk = 0; blk < 12; ++blk) {
    u16* Wq_b = WqA + (size_t)(hoist ? blk : 0) * QSZ;
    u16* W1_b = W1A + (size_t)(hoist ? blk : 0) * WSZ;
    u16* W2_b = W2A + (size_t)(hoist ? blk : 0) * WSZ;
    ln_kernel<<<MPAD / 4, 256, 0, stream>>>(X, ln1_g + blk * 768, ln1_b + blk * 768, Aln);
    if (!hoist)
      prep_kernel<<<(PREP_N + 255) / 256, 256, 0, stream>>>(
          qw, kw, vw, w1, w2, Wq_b, W1_b, W2_b, blk);
    qkv_flat<<<768, 256, 0, stream>>>(
        Aln, Wq_b, qb + blk * 768, kb + blk * 768, vb + blk * 768,
        Qb, Kb, Vtb, (MPAD / 128) * 18, 768);
    attn_kernel<<<BHN, 256, 0, stream>>>(Qb, Kb, Vtb, X);
    ln_kernel<<<MPAD / 4, 256, 0, stream>>>(X, ln2_g + blk * 768, ln2_b + blk * 768, Aln);
    gemm128f_gelu<<<768, 256, 0, stream>>>(Aln, W1_b, b1 + blk * 3072, Hb, 2376, 768);
    gemm128<EPI_RESID><<<(MPAD / 128) * (768 / 128), 256, 0, stream>>>(
        Hb, W2_b, 3072, 3072, 3072, MPAD / 128, 768 / 128,
        b2 + blk * 768, nullptr, nullptr, X, nullptr, nullptr, nullptr, nullptr);
  }

  head_kernel<<<NB, 256, 0, stream>>>(X, head_w, head_b, (float*)d_out);
}